// Round 4
// baseline (716.115 us; speedup 1.0000x reference)
//
#include <hip/hip_runtime.h>
#include <stdint.h>

#define IN_DIM 4096
#define OUT_DIM 11008
#define TOKENS 8192
#define WN (45088768L)   // OUT_DIM * IN_DIM (elements)
#define NKT 64           // K-tiles of 64

typedef int int4v __attribute__((ext_vector_type(4)));

__device__ __forceinline__ float bf2f(uint32_t u16) {
  union { uint32_t i; float f; } v; v.i = u16 << 16; return v.f;
}
// norm_weight is exactly all-ones: first u16 = 0x3F80 iff bf16, 0x0000 iff fp32 (LE).
__device__ __forceinline__ bool probe_bf16(const void* nw) {
  return ((const uint16_t*)nw)[0] == 0x3F80u;
}

// ---------------- K1: partial sum of |w| (deterministic, double acc) ----------------
__global__ __launch_bounds__(256) void k_wabs(const void* __restrict__ wv,
                                              const void* __restrict__ nwv,
                                              double* __restrict__ partial) {
  const bool b16 = probe_bf16(nwv);
  const long tid = (long)blockIdx.x * 256 + threadIdx.x;
  const long stride = (long)gridDim.x * 256;
  double s = 0.0;
  if (b16) {
    const uint4* w = (const uint4*)wv;          // 8 bf16 per chunk
    for (long i = tid; i < WN / 8; i += stride) {
      uint4 v = w[i];
      uint32_t a[4] = {v.x, v.y, v.z, v.w};
      float t = 0.f;
#pragma unroll
      for (int j = 0; j < 4; j++)
        t += fabsf(bf2f(a[j] & 0xffffu)) + fabsf(bf2f(a[j] >> 16));
      s += (double)t;
    }
  } else {
    const float4* w = (const float4*)wv;        // 4 fp32 per chunk
    for (long i = tid; i < WN / 4; i += stride) {
      float4 v = w[i];
      s += (double)(fabsf(v.x) + fabsf(v.y) + fabsf(v.z) + fabsf(v.w));
    }
  }
#pragma unroll
  for (int off = 32; off > 0; off >>= 1) s += __shfl_down(s, off);
  __shared__ double sd[4];
  if ((threadIdx.x & 63) == 0) sd[threadIdx.x >> 6] = s;
  __syncthreads();
  if (threadIdx.x == 0) partial[blockIdx.x] = (sd[0] + sd[1]) + (sd[2] + sd[3]);
}

// ---------------- K2: final reduce -> wscale ----------------
__global__ __launch_bounds__(256) void k_wscale(const double* __restrict__ partial,
                                                float* __restrict__ hdr) {
  double s = 0.0;
  for (int i = threadIdx.x; i < 2048; i += 256) s += partial[i];
#pragma unroll
  for (int off = 32; off > 0; off >>= 1) s += __shfl_down(s, off);
  __shared__ double sd[4];
  if ((threadIdx.x & 63) == 0) sd[threadIdx.x >> 6] = s;
  __syncthreads();
  if (threadIdx.x == 0) {
    double mean = ((sd[0] + sd[1]) + (sd[2] + sd[3])) / (double)WN;
    float meanc = (float)mean;
    if (meanc < 1e-5f) meanc = 1e-5f;
    float wscale = 1.0f / meanc;   // np: scale = 1/clip(mean|w|,1e-5)
    hdr[0] = wscale;
    hdr[1] = 1.0f / wscale;        // multiply-back factor (= clipped mean)
  }
}

// ---------------- K3: RMSNorm + per-token absmax int8 quant ----------------
__global__ __launch_bounds__(256) void k_act(const void* __restrict__ xv,
                                             const void* __restrict__ nwv,
                                             int8_t* __restrict__ qx,
                                             float* __restrict__ invsx) {
  const bool b16 = probe_bf16(nwv);
  const int t = blockIdx.x;
  const int tx = threadIdx.x;
  float xw[16];                 // this thread owns elements [tx*16, tx*16+16)
  float ss = 0.f, mx = 0.f;
  if (b16) {
    const uint16_t* xr = (const uint16_t*)xv + (long)t * IN_DIM;
    const uint16_t* nw = (const uint16_t*)nwv;
#pragma unroll
    for (int c = 0; c < 2; c++) {
      uint4 vx = ((const uint4*)xr)[tx * 2 + c];
      uint4 vn = ((const uint4*)nw)[tx * 2 + c];
      uint32_t ax[4] = {vx.x, vx.y, vx.z, vx.w};
      uint32_t an[4] = {vn.x, vn.y, vn.z, vn.w};
#pragma unroll
      for (int j = 0; j < 4; j++) {
        float x0 = bf2f(ax[j] & 0xffffu), x1 = bf2f(ax[j] >> 16);
        float n0 = bf2f(an[j] & 0xffffu), n1 = bf2f(an[j] >> 16);
        ss += x0 * x0 + x1 * x1;
        float p0 = x0 * n0, p1 = x1 * n1;
        xw[c * 8 + j * 2]     = p0;
        xw[c * 8 + j * 2 + 1] = p1;
        mx = fmaxf(mx, fmaxf(fabsf(p0), fabsf(p1)));
      }
    }
  } else {
    const float* xr = (const float*)xv + (long)t * IN_DIM;
    const float* nw = (const float*)nwv;
#pragma unroll
    for (int c = 0; c < 4; c++) {
      float4 vx = ((const float4*)xr)[tx * 4 + c];
      float4 vn = ((const float4*)nw)[tx * 4 + c];
      ss += vx.x * vx.x + vx.y * vx.y + vx.z * vx.z + vx.w * vx.w;
      float p0 = vx.x * vn.x, p1 = vx.y * vn.y, p2 = vx.z * vn.z, p3 = vx.w * vn.w;
      xw[c * 4 + 0] = p0; xw[c * 4 + 1] = p1; xw[c * 4 + 2] = p2; xw[c * 4 + 3] = p3;
      mx = fmaxf(mx, fmaxf(fmaxf(fabsf(p0), fabsf(p1)), fmaxf(fabsf(p2), fabsf(p3))));
    }
  }
#pragma unroll
  for (int off = 32; off > 0; off >>= 1) {
    ss += __shfl_down(ss, off);
    mx = fmaxf(mx, __shfl_down(mx, off));
  }
  __shared__ float s_ss[4], s_mx[4];
  __shared__ float bc[1];
  if ((tx & 63) == 0) { s_ss[tx >> 6] = ss; s_mx[tx >> 6] = mx; }
  __syncthreads();
  if (tx == 0) {
    float sst = (s_ss[0] + s_ss[1]) + (s_ss[2] + s_ss[3]);
    float mxt = fmaxf(fmaxf(s_mx[0], s_mx[1]), fmaxf(s_mx[2], s_mx[3]));
    float var = sst / (float)IN_DIM;
    float rms = 1.0f / sqrtf(var + 1e-6f);
    float amax = rms * mxt;                 // absmax of x*rms*nw (rms>0 uniform)
    if (amax < 1e-5f) amax = 1e-5f;
    float scale = 127.0f / amax;
    bc[0] = rms * scale;
    invsx[t] = 1.0f / scale;                // np divides q by scale
  }
  __syncthreads();
  float rsc = bc[0];
  uint32_t pw[4];
#pragma unroll
  for (int d = 0; d < 4; d++) {
    uint32_t v = 0;
#pragma unroll
    for (int j = 0; j < 4; j++) {
      float q = rintf(xw[d * 4 + j] * rsc);  // round-half-even == jnp.round
      q = fminf(fmaxf(q, -128.f), 127.f);
      int qi = (int)q;
      v |= ((uint32_t)(qi & 0xff)) << (8 * j);
    }
    pw[d] = v;
  }
  uint4 st; st.x = pw[0]; st.y = pw[1]; st.z = pw[2]; st.w = pw[3];
  ((uint4*)(qx + (long)t * IN_DIM))[tx] = st;
}

// ---------------- K4: ternary weight quant + 2:4 keep-first-2-nonzeros mask ----------------
__global__ __launch_bounds__(256) void k_wq(const void* __restrict__ wv,
                                            const void* __restrict__ nwv,
                                            const float* __restrict__ hdr,
                                            int8_t* __restrict__ qw) {
  const bool b16 = probe_bf16(nwv);
  const long i = (long)blockIdx.x * 256 + threadIdx.x;  // chunk of 8 elems
  const float wscale = hdr[0];
  float f[8];
  if (b16) {
    uint4 v = ((const uint4*)wv)[i];
    uint32_t a[4] = {v.x, v.y, v.z, v.w};
#pragma unroll
    for (int j = 0; j < 4; j++) {
      f[j * 2]     = bf2f(a[j] & 0xffffu);
      f[j * 2 + 1] = bf2f(a[j] >> 16);
    }
  } else {
    float4 v0 = ((const float4*)wv)[i * 2];
    float4 v1 = ((const float4*)wv)[i * 2 + 1];
    f[0] = v0.x; f[1] = v0.y; f[2] = v0.z; f[3] = v0.w;
    f[4] = v1.x; f[5] = v1.y; f[6] = v1.z; f[7] = v1.w;
  }
  int q[8];
#pragma unroll
  for (int j = 0; j < 8; j++) {
    float qf = rintf(f[j] * wscale);
    qf = fminf(fmaxf(qf, -1.f), 1.f);
    q[j] = (int)qf;
  }
  // top_k(|w_q|, 2): all nonzero |w_q| equal + lax.top_k lower-index tie-break
  // == keep the first 2 nonzeros per group of 4
#pragma unroll
  for (int g = 0; g < 2; g++) {
    int cnt = 0;
#pragma unroll
    for (int j = 0; j < 4; j++) {
      int idx = g * 4 + j;
      if (q[idx] != 0) { cnt++; if (cnt > 2) q[idx] = 0; }
    }
  }
  uint32_t lo = 0, hi = 0;
#pragma unroll
  for (int j = 0; j < 4; j++) lo |= ((uint32_t)(q[j] & 0xff)) << (8 * j);
#pragma unroll
  for (int j = 0; j < 4; j++) hi |= ((uint32_t)(q[4 + j] & 0xff)) << (8 * j);
  uint2 st; st.x = lo; st.y = hi;
  ((uint2*)qw)[i] = st;
}

// ---------------- K5: int8 GEMM, 256x256 tile, 4-deep LDS ring, counted vmcnt ----------------
// out[t][o] = sum_k qx[t][k]*qw[o][k] * invsx[t]*winv
__global__ __launch_bounds__(512, 2) void k_gemm(const int8_t* __restrict__ qx,
                                                 const int8_t* __restrict__ qw,
                                                 const float* __restrict__ invsx,
                                                 const float* __restrict__ hdr,
                                                 float* __restrict__ out) {
  // 4-deep ring: 4 x (256 rows x 64 B) per matrix = 64 KiB each, 128 KiB total
  __shared__ __align__(16) int8_t sA[4][256 * 64];
  __shared__ __align__(16) int8_t sB[4][256 * 64];

  const int tx = threadIdx.x;          // 0..511
  const int wave = tx >> 6, lane = tx & 63;
  const int wr = wave >> 2, wc = wave & 3;      // 2 x 4 wave grid
  const int lr = lane & 15;                     // fragment row within 16-tile
  const int sl = lane >> 4;                     // k-slot (16B) within 64B row

  // XCD-aware bijective swizzle: 1376 blocks = 8 XCDs x 172
  const int bid = blockIdx.x;
  const int swz = (bid & 7) * 172 + (bid >> 3);
  const int bm = swz & 31;            // 32 m-blocks (m-major within XCD chunk -> B-panel reuse)
  const int bn = swz >> 5;            // 43 n-blocks
  const int m0 = bm * 256, n0 = bn * 256;

  // ---- staging: pre-swizzled global source (LDS write is linear; read applies same XOR) ----
  // round covers 128 rows x 64 B; thread -> row = tx>>2, slot = tx&3, swizzled slot = slot ^ ((row>>1)&3)
  const int srow  = tx >> 2;
  const int scol  = ((tx & 3) ^ ((tx >> 3) & 3)) * 16;
  const int8_t* gA = qx + (long)(m0 + srow) * IN_DIM + scol;
  const int8_t* gB = qw + (long)(n0 + srow) * IN_DIM + scol;

  auto STAGE = [&](int t) {
    const int b = t & 3;
    const long ko = (long)t * 64;
    __builtin_amdgcn_global_load_lds(
        (const __attribute__((address_space(1))) void*)(gA + ko),
        (__attribute__((address_space(3))) void*)(&sA[b][wave * 1024]), 16, 0, 0);
    __builtin_amdgcn_global_load_lds(
        (const __attribute__((address_space(1))) void*)(gA + ko + 128L * IN_DIM),
        (__attribute__((address_space(3))) void*)(&sA[b][8192 + wave * 1024]), 16, 0, 0);
    __builtin_amdgcn_global_load_lds(
        (const __attribute__((address_space(1))) void*)(gB + ko),
        (__attribute__((address_space(3))) void*)(&sB[b][wave * 1024]), 16, 0, 0);
    __builtin_amdgcn_global_load_lds(
        (const __attribute__((address_space(1))) void*)(gB + ko + 128L * IN_DIM),
        (__attribute__((address_space(3))) void*)(&sB[b][8192 + wave * 1024]), 16, 0, 0);
  };

  // ---- fragment LDS offsets (swizzled read side) ----
  int offA[8], offB[4];
#pragma unroll
  for (int mi = 0; mi < 8; mi++) {
    const int row = wr * 128 + mi * 16 + lr;
    offA[mi] = row * 64 + ((sl ^ ((row >> 1) & 3)) * 16);
  }
#pragma unroll
  for (int ni = 0; ni < 4; ni++) {
    const int row = wc * 64 + ni * 16 + lr;
    offB[ni] = row * 64 + ((sl ^ ((row >> 1) & 3)) * 16);
  }

  int4v acc[8][4];
#pragma unroll
  for (int mi = 0; mi < 8; mi++)
#pragma unroll
    for (int ni = 0; ni < 4; ni++) { acc[mi][ni][0] = 0; acc[mi][ni][1] = 0; acc[mi][ni][2] = 0; acc[mi][ni][3] = 0; }

  // prologue: 3 tiles in flight
  STAGE(0); STAGE(1); STAGE(2);

#define TILE_BODY(T, WAITINSN)                                          \
  {                                                                     \
    asm volatile(WAITINSN ::: "memory");                                \
    __builtin_amdgcn_s_barrier();                                       \
    __builtin_amdgcn_sched_barrier(0);                                  \
    const int b_ = (T) & 3;                                             \
    if ((T) + 3 < NKT) STAGE((T) + 3);                                  \
    int4v a_[8], bb_[4];                                                \
    _Pragma("unroll") for (int mi = 0; mi < 8; ++mi)                    \
        a_[mi] = *(const int4v*)(&sA[b_][offA[mi]]);                    \
    _Pragma("unroll") for (int ni = 0; ni < 4; ++ni)                    \
        bb_[ni] = *(const int4v*)(&sB[b_][offB[ni]]);                   \
    __builtin_amdgcn_s_setprio(1);                                      \
    _Pragma("unroll") for (int mi = 0; mi < 8; ++mi)                    \
      _Pragma("unroll") for (int ni = 0; ni < 4; ++ni)                  \
          acc[mi][ni] = __builtin_amdgcn_mfma_i32_16x16x64_i8(          \
              a_[mi], bb_[ni], acc[mi][ni], 0, 0, 0);                   \
    __builtin_amdgcn_s_setprio(0);                                      \
  }

  for (int t = 0; t < NKT - 2; ++t) TILE_BODY(t, "s_waitcnt vmcnt(8)");
  TILE_BODY(NKT - 2, "s_waitcnt vmcnt(4)");
  TILE_BODY(NKT - 1, "s_waitcnt vmcnt(0)");
#undef TILE_BODY

  // ---- epilogue: scale and store fp32 ----
  const float winv = hdr[1];
#pragma unroll
  for (int mi = 0; mi < 8; mi++) {
    const int rbase = m0 + wr * 128 + mi * 16 + (lane >> 4) * 4;
#pragma unroll
    for (int r = 0; r < 4; r++) {
      const int trow = rbase + r;
      const float fs = invsx[trow] * winv;
      const long ob = (long)trow * OUT_DIM + n0 + wc * 64 + lr;
#pragma unroll
      for (int ni = 0; ni < 4; ni++) {
        out[ob + ni * 16] = (float)acc[mi][ni][r] * fs;
      }
    }
  }
}

extern "C" void kernel_launch(void* const* d_in, const int* in_sizes, int n_in,
                              void* d_out, int out_size, void* d_ws, size_t ws_size,
                              hipStream_t stream) {
  const void* x  = d_in[0];   // [4,2048,4096]  fp32 (bf16 auto-probed fallback)
  const void* w  = d_in[1];   // [11008,4096]
  const void* nw = d_in[2];   // [4096], exactly ones -> dtype probe
  float* out = (float*)d_out; // fp32 [8192,11008]

  char* ws = (char*)d_ws;
  float*  hdr     = (float*)ws;                    // [0]=wscale, [1]=1/wscale
  double* partial = (double*)(ws + 1024);          // 2048 doubles
  float*  invsx   = (float*)(ws + 20480);          // 8192 floats
  int8_t* qx      = (int8_t*)(ws + (1L << 20));            // 32 MB
  int8_t* qw      = (int8_t*)(ws + 36L * (1L << 20));      // 44 MB

  hipLaunchKernelGGL(k_wabs,   dim3(2048),   dim3(256), 0, stream, w, nw, partial);
  hipLaunchKernelGGL(k_wscale, dim3(1),      dim3(256), 0, stream, partial, hdr);
  hipLaunchKernelGGL(k_act,    dim3(TOKENS), dim3(256), 0, stream, x, nw, qx, invsx);
  hipLaunchKernelGGL(k_wq,     dim3(22016),  dim3(256), 0, stream, w, nw, hdr, qw);
  hipLaunchKernelGGL(k_gemm,   dim3(32 * 43), dim3(512), 0, stream,
                     qx, qw, invsx, hdr, out);
}

// Round 5
// 611.802 us; speedup vs baseline: 1.1705x; 1.1705x over previous
//
#include <hip/hip_runtime.h>
#include <stdint.h>

#define IN_DIM 4096
#define OUT_DIM 11008
#define TOKENS 8192
#define WN (45088768L)   // OUT_DIM * IN_DIM (elements)
#define NKT128 32        // K-tiles of 128 bytes (elements)

typedef int int4v __attribute__((ext_vector_type(4)));
#define AS1 __attribute__((address_space(1)))
#define AS3 __attribute__((address_space(3)))

__device__ __forceinline__ float bf2f(uint32_t u16) {
  union { uint32_t i; float f; } v; v.i = u16 << 16; return v.f;
}
// norm_weight is exactly all-ones: first u16 = 0x3F80 iff bf16, 0x0000 iff fp32 (LE).
__device__ __forceinline__ bool probe_bf16(const void* nw) {
  return ((const uint16_t*)nw)[0] == 0x3F80u;
}

// ---------------- K1: partial sum of |w| (deterministic, double acc) ----------------
__global__ __launch_bounds__(256) void k_wabs(const void* __restrict__ wv,
                                              const void* __restrict__ nwv,
                                              double* __restrict__ partial) {
  const bool b16 = probe_bf16(nwv);
  const long tid = (long)blockIdx.x * 256 + threadIdx.x;
  const long stride = (long)gridDim.x * 256;
  double s = 0.0;
  if (b16) {
    const uint4* w = (const uint4*)wv;          // 8 bf16 per chunk
    for (long i = tid; i < WN / 8; i += stride) {
      uint4 v = w[i];
      uint32_t a[4] = {v.x, v.y, v.z, v.w};
      float t = 0.f;
#pragma unroll
      for (int j = 0; j < 4; j++)
        t += fabsf(bf2f(a[j] & 0xffffu)) + fabsf(bf2f(a[j] >> 16));
      s += (double)t;
    }
  } else {
    const float4* w = (const float4*)wv;        // 4 fp32 per chunk
    for (long i = tid; i < WN / 4; i += stride) {
      float4 v = w[i];
      s += (double)(fabsf(v.x) + fabsf(v.y) + fabsf(v.z) + fabsf(v.w));
    }
  }
#pragma unroll
  for (int off = 32; off > 0; off >>= 1) s += __shfl_down(s, off);
  __shared__ double sd[4];
  if ((threadIdx.x & 63) == 0) sd[threadIdx.x >> 6] = s;
  __syncthreads();
  if (threadIdx.x == 0) partial[blockIdx.x] = (sd[0] + sd[1]) + (sd[2] + sd[3]);
}

// ---------------- K2: final reduce -> wscale ----------------
__global__ __launch_bounds__(256) void k_wscale(const double* __restrict__ partial,
                                                float* __restrict__ hdr) {
  double s = 0.0;
  for (int i = threadIdx.x; i < 2048; i += 256) s += partial[i];
#pragma unroll
  for (int off = 32; off > 0; off >>= 1) s += __shfl_down(s, off);
  __shared__ double sd[4];
  if ((threadIdx.x & 63) == 0) sd[threadIdx.x >> 6] = s;
  __syncthreads();
  if (threadIdx.x == 0) {
    double mean = ((sd[0] + sd[1]) + (sd[2] + sd[3])) / (double)WN;
    float meanc = (float)mean;
    if (meanc < 1e-5f) meanc = 1e-5f;
    float wscale = 1.0f / meanc;   // np: scale = 1/clip(mean|w|,1e-5)
    hdr[0] = wscale;
    hdr[1] = 1.0f / wscale;        // multiply-back factor (= clipped mean)
  }
}

// ---------------- K3: RMSNorm + per-token absmax int8 quant ----------------
__global__ __launch_bounds__(256) void k_act(const void* __restrict__ xv,
                                             const void* __restrict__ nwv,
                                             int8_t* __restrict__ qx,
                                             float* __restrict__ invsx) {
  const bool b16 = probe_bf16(nwv);
  const int t = blockIdx.x;
  const int tx = threadIdx.x;
  float xw[16];                 // this thread owns elements [tx*16, tx*16+16)
  float ss = 0.f, mx = 0.f;
  if (b16) {
    const uint16_t* xr = (const uint16_t*)xv + (long)t * IN_DIM;
    const uint16_t* nw = (const uint16_t*)nwv;
#pragma unroll
    for (int c = 0; c < 2; c++) {
      uint4 vx = ((const uint4*)xr)[tx * 2 + c];
      uint4 vn = ((const uint4*)nw)[tx * 2 + c];
      uint32_t ax[4] = {vx.x, vx.y, vx.z, vx.w};
      uint32_t an[4] = {vn.x, vn.y, vn.z, vn.w};
#pragma unroll
      for (int j = 0; j < 4; j++) {
        float x0 = bf2f(ax[j] & 0xffffu), x1 = bf2f(ax[j] >> 16);
        float n0 = bf2f(an[j] & 0xffffu), n1 = bf2f(an[j] >> 16);
        ss += x0 * x0 + x1 * x1;
        float p0 = x0 * n0, p1 = x1 * n1;
        xw[c * 8 + j * 2]     = p0;
        xw[c * 8 + j * 2 + 1] = p1;
        mx = fmaxf(mx, fmaxf(fabsf(p0), fabsf(p1)));
      }
    }
  } else {
    const float* xr = (const float*)xv + (long)t * IN_DIM;
    const float* nw = (const float*)nwv;
#pragma unroll
    for (int c = 0; c < 4; c++) {
      float4 vx = ((const float4*)xr)[tx * 4 + c];
      float4 vn = ((const float4*)nw)[tx * 4 + c];
      ss += vx.x * vx.x + vx.y * vx.y + vx.z * vx.z + vx.w * vx.w;
      float p0 = vx.x * vn.x, p1 = vx.y * vn.y, p2 = vx.z * vn.z, p3 = vx.w * vn.w;
      xw[c * 4 + 0] = p0; xw[c * 4 + 1] = p1; xw[c * 4 + 2] = p2; xw[c * 4 + 3] = p3;
      mx = fmaxf(mx, fmaxf(fmaxf(fabsf(p0), fabsf(p1)), fmaxf(fabsf(p2), fabsf(p3))));
    }
  }
#pragma unroll
  for (int off = 32; off > 0; off >>= 1) {
    ss += __shfl_down(ss, off);
    mx = fmaxf(mx, __shfl_down(mx, off));
  }
  __shared__ float s_ss[4], s_mx[4];
  __shared__ float bc[1];
  if ((tx & 63) == 0) { s_ss[tx >> 6] = ss; s_mx[tx >> 6] = mx; }
  __syncthreads();
  if (tx == 0) {
    float sst = (s_ss[0] + s_ss[1]) + (s_ss[2] + s_ss[3]);
    float mxt = fmaxf(fmaxf(s_mx[0], s_mx[1]), fmaxf(s_mx[2], s_mx[3]));
    float var = sst / (float)IN_DIM;
    float rms = 1.0f / sqrtf(var + 1e-6f);
    float amax = rms * mxt;                 // absmax of x*rms*nw (rms>0 uniform)
    if (amax < 1e-5f) amax = 1e-5f;
    float scale = 127.0f / amax;
    bc[0] = rms * scale;
    invsx[t] = 1.0f / scale;                // np divides q by scale
  }
  __syncthreads();
  float rsc = bc[0];
  uint32_t pw[4];
#pragma unroll
  for (int d = 0; d < 4; d++) {
    uint32_t v = 0;
#pragma unroll
    for (int j = 0; j < 4; j++) {
      float q = rintf(xw[d * 4 + j] * rsc);  // round-half-even == jnp.round
      q = fminf(fmaxf(q, -128.f), 127.f);
      int qi = (int)q;
      v |= ((uint32_t)(qi & 0xff)) << (8 * j);
    }
    pw[d] = v;
  }
  uint4 st; st.x = pw[0]; st.y = pw[1]; st.z = pw[2]; st.w = pw[3];
  ((uint4*)(qx + (long)t * IN_DIM))[tx] = st;
}

// ---------------- K4: ternary weight quant + 2:4 keep-first-2-nonzeros mask ----------------
__global__ __launch_bounds__(256) void k_wq(const void* __restrict__ wv,
                                            const void* __restrict__ nwv,
                                            const float* __restrict__ hdr,
                                            int8_t* __restrict__ qw) {
  const bool b16 = probe_bf16(nwv);
  const long i = (long)blockIdx.x * 256 + threadIdx.x;  // chunk of 8 elems
  const float wscale = hdr[0];
  float f[8];
  if (b16) {
    uint4 v = ((const uint4*)wv)[i];
    uint32_t a[4] = {v.x, v.y, v.z, v.w};
#pragma unroll
    for (int j = 0; j < 4; j++) {
      f[j * 2]     = bf2f(a[j] & 0xffffu);
      f[j * 2 + 1] = bf2f(a[j] >> 16);
    }
  } else {
    float4 v0 = ((const float4*)wv)[i * 2];
    float4 v1 = ((const float4*)wv)[i * 2 + 1];
    f[0] = v0.x; f[1] = v0.y; f[2] = v0.z; f[3] = v0.w;
    f[4] = v1.x; f[5] = v1.y; f[6] = v1.z; f[7] = v1.w;
  }
  int q[8];
#pragma unroll
  for (int j = 0; j < 8; j++) {
    float qf = rintf(f[j] * wscale);
    qf = fminf(fmaxf(qf, -1.f), 1.f);
    q[j] = (int)qf;
  }
  // top_k(|w_q|, 2): equal nonzero magnitudes + lax.top_k lower-index tie-break
  // == keep the first 2 nonzeros per group of 4
#pragma unroll
  for (int g = 0; g < 2; g++) {
    int cnt = 0;
#pragma unroll
    for (int j = 0; j < 4; j++) {
      int idx = g * 4 + j;
      if (q[idx] != 0) { cnt++; if (cnt > 2) q[idx] = 0; }
    }
  }
  uint32_t lo = 0, hi = 0;
#pragma unroll
  for (int j = 0; j < 4; j++) lo |= ((uint32_t)(q[j] & 0xff)) << (8 * j);
#pragma unroll
  for (int j = 0; j < 4; j++) hi |= ((uint32_t)(q[4 + j] & 0xff)) << (8 * j);
  uint2 st; st.x = lo; st.y = hi;
  ((uint2*)qw)[i] = st;
}

// ---------------- K5: int8 GEMM, 256x256 tile, m201 8-phase schedule (4 phases/K-tile) ----
// out[t][o] = sum_k qx[t][k]*qw[o][k] * invsx[t]*winv
__global__ __launch_bounds__(512, 2) void k_gemm(const int8_t* __restrict__ qx,
                                                 const int8_t* __restrict__ qw,
                                                 const float* __restrict__ invsx,
                                                 const float* __restrict__ hdr,
                                                 float* __restrict__ out) {
  // 2-deep double-buffer: per K-tile A = 256 rows x 128 B = 32 KB, B same. Total 128 KiB.
  __shared__ __align__(16) int8_t sA[2][256 * 128];
  __shared__ __align__(16) int8_t sB[2][256 * 128];

  const int tx = threadIdx.x;          // 0..511
  const int wave = tx >> 6, lane = tx & 63;
  const int wr = wave >> 2, wc = wave & 3;      // 2 x 4 wave grid
  const int fr = lane & 15;                     // fragment row within 16-tile
  const int fg = lane >> 4;                     // k-group (16B) within 64B k-step

  // XCD-aware bijective swizzle: 1376 blocks = 8 XCDs x 172
  const int bid = blockIdx.x;
  const int swz = (bid & 7) * 172 + (bid >> 3);
  const int m0 = (swz & 31) * 256;    // 32 m-blocks
  const int n0 = (swz >> 5) * 256;    // 43 n-blocks

  // ---- staging: pre-swizzled global source; LDS write is linear (base+lane*16) ----
  // per load: 64 rows x 128B; thread -> row=tx>>3, slot=tx&7, src slot = slot ^ ((row>>1)&7)
  const int srow = tx >> 3;
  const int scol = ((tx & 7) ^ ((tx >> 4) & 7)) * 16;
  const int8_t* gA = qx + (long)(m0 + srow) * IN_DIM + scol;
  const int8_t* gB = qw + (long)(n0 + srow) * IN_DIM + scol;
  int8_t* const sA0 = &sA[0][0];
  int8_t* const sB0 = &sB[0][0];

  auto stageA = [&](int t, int half) {
    if (t >= NKT128) return;
    int8_t* base = sA0 + (t & 1) * (256 * 128);
#pragma unroll
    for (int l = 0; l < 2; ++l) {
      const int rb = half * 128 + l * 64;
      __builtin_amdgcn_global_load_lds(
          (const AS1 void*)(gA + (long)t * 128 + (long)rb * IN_DIM),
          (AS3 void*)(base + rb * 128 + wave * 1024), 16, 0, 0);
    }
  };
  auto stageB = [&](int t, int half) {
    if (t >= NKT128) return;
    int8_t* base = sB0 + (t & 1) * (256 * 128);
#pragma unroll
    for (int l = 0; l < 2; ++l) {
      const int rb = half * 128 + l * 64;
      __builtin_amdgcn_global_load_lds(
          (const AS1 void*)(gB + (long)t * 128 + (long)rb * IN_DIM),
          (AS3 void*)(base + rb * 128 + wave * 1024), 16, 0, 0);
    }
  };

  // ---- fragment LDS byte offsets (read side applies the same 3-bit XOR) ----
  int offA[8][2], offB[4][2];
#pragma unroll
  for (int mi = 0; mi < 8; ++mi) {
    const int row = wr * 128 + mi * 16 + fr;
    const int xr = (row >> 1) & 7;
#pragma unroll
    for (int ks = 0; ks < 2; ++ks)
      offA[mi][ks] = row * 128 + (((ks * 4 + fg) ^ xr) * 16);
  }
#pragma unroll
  for (int ni = 0; ni < 4; ++ni) {
    const int row = wc * 64 + ni * 16 + fr;
    const int xr = (row >> 1) & 7;
#pragma unroll
    for (int ks = 0; ks < 2; ++ks)
      offB[ni][ks] = row * 128 + (((ks * 4 + fg) ^ xr) * 16);
  }

  int4v acc[8][4];
#pragma unroll
  for (int mi = 0; mi < 8; ++mi)
#pragma unroll
    for (int ni = 0; ni < 4; ++ni) {
      acc[mi][ni][0] = 0; acc[mi][ni][1] = 0; acc[mi][ni][2] = 0; acc[mi][ni][3] = 0;
    }

  // ---- prologue: tile 0 (all 4 halves) + tile 1 A halves = 12 loads ----
  stageA(0, 0); stageA(0, 1); stageB(0, 0); stageB(0, 1);
  stageA(1, 0); stageA(1, 1);
  asm volatile("s_waitcnt vmcnt(4)" ::: "memory");   // tile 0 landed; A(1) in flight
  __builtin_amdgcn_s_barrier();

  int4v a[8][2];   // A frags, current K-tile
  int4v bf[2][2];  // B frags, reused between {ni 0,1} and {ni 2,3}

#pragma unroll 2
  for (int t = 0; t < NKT128; ++t) {
    const int bofs = (t & 1) * (256 * 128);

    // ===== phase 1: read b[0..1], a[0..3]; stage B-lo(t+1); MFMA Q(m-lo, n-lo) =====
#pragma unroll
    for (int j = 0; j < 2; ++j) {
      bf[j][0] = *(const int4v*)(sB0 + bofs + offB[j][0]);
      bf[j][1] = *(const int4v*)(sB0 + bofs + offB[j][1]);
    }
#pragma unroll
    for (int mi = 0; mi < 4; ++mi) {
      a[mi][0] = *(const int4v*)(sA0 + bofs + offA[mi][0]);
      a[mi][1] = *(const int4v*)(sA0 + bofs + offA[mi][1]);
    }
    stageB(t + 1, 0);
    asm volatile("s_waitcnt lgkmcnt(8)" ::: "memory");
    __builtin_amdgcn_s_barrier();
    asm volatile("s_waitcnt lgkmcnt(0)" ::: "memory");
    __builtin_amdgcn_s_setprio(1);
#pragma unroll
    for (int mi = 0; mi < 4; ++mi)
#pragma unroll
      for (int j = 0; j < 2; ++j)
#pragma unroll
        for (int ks = 0; ks < 2; ++ks)
          acc[mi][j] = __builtin_amdgcn_mfma_i32_16x16x64_i8(a[mi][ks], bf[j][ks], acc[mi][j], 0, 0, 0);
    __builtin_amdgcn_s_setprio(0);
    __builtin_amdgcn_s_barrier();

    // ===== phase 2: read a[4..7]; stage B-hi(t+1); MFMA Q(m-hi, n-lo) =====
#pragma unroll
    for (int mi = 4; mi < 8; ++mi) {
      a[mi][0] = *(const int4v*)(sA0 + bofs + offA[mi][0]);
      a[mi][1] = *(const int4v*)(sA0 + bofs + offA[mi][1]);
    }
    stageB(t + 1, 1);
    __builtin_amdgcn_s_barrier();
    asm volatile("s_waitcnt lgkmcnt(0)" ::: "memory");
    __builtin_amdgcn_s_setprio(1);
#pragma unroll
    for (int mi = 4; mi < 8; ++mi)
#pragma unroll
      for (int j = 0; j < 2; ++j)
#pragma unroll
        for (int ks = 0; ks < 2; ++ks)
          acc[mi][j] = __builtin_amdgcn_mfma_i32_16x16x64_i8(a[mi][ks], bf[j][ks], acc[mi][j], 0, 0, 0);
    __builtin_amdgcn_s_setprio(0);
    __builtin_amdgcn_s_barrier();

    // ===== phase 3: read b[2..3]; stage A-lo(t+2); MFMA Q(m-lo, n-hi) =====
#pragma unroll
    for (int j = 0; j < 2; ++j) {
      bf[j][0] = *(const int4v*)(sB0 + bofs + offB[2 + j][0]);
      bf[j][1] = *(const int4v*)(sB0 + bofs + offB[2 + j][1]);
    }
    stageA(t + 2, 0);
    __builtin_amdgcn_s_barrier();
    asm volatile("s_waitcnt lgkmcnt(0)" ::: "memory");
    __builtin_amdgcn_s_setprio(1);
#pragma unroll
    for (int mi = 0; mi < 4; ++mi)
#pragma unroll
      for (int j = 0; j < 2; ++j)
#pragma unroll
        for (int ks = 0; ks < 2; ++ks)
          acc[mi][2 + j] = __builtin_amdgcn_mfma_i32_16x16x64_i8(a[mi][ks], bf[j][ks], acc[mi][2 + j], 0, 0, 0);
    __builtin_amdgcn_s_setprio(0);
    __builtin_amdgcn_s_barrier();

    // ===== phase 4: stage A-hi(t+2); counted vmcnt; MFMA Q(m-hi, n-hi) =====
    stageA(t + 2, 1);
    if (t < NKT128 - 2) {
      asm volatile("s_waitcnt vmcnt(4)" ::: "memory");  // allow A(t+2) in flight
    } else {
      asm volatile("s_waitcnt vmcnt(0)" ::: "memory");  // drain for last tiles
    }
    __builtin_amdgcn_s_barrier();
    __builtin_amdgcn_s_setprio(1);
#pragma unroll
    for (int mi = 4; mi < 8; ++mi)
#pragma unroll
      for (int j = 0; j < 2; ++j)
#pragma unroll
        for (int ks = 0; ks < 2; ++ks)
          acc[mi][2 + j] = __builtin_amdgcn_mfma_i32_16x16x64_i8(a[mi][ks], bf[j][ks], acc[mi][2 + j], 0, 0, 0);
    __builtin_amdgcn_s_setprio(0);
    __builtin_amdgcn_s_barrier();
  }

  // ---- epilogue: scale and store fp32 ----
  const float winv = hdr[1];
#pragma unroll
  for (int mi = 0; mi < 8; ++mi) {
    const int rbase = m0 + wr * 128 + mi * 16 + (lane >> 4) * 4;
#pragma unroll
    for (int r = 0; r < 4; ++r) {
      const int trow = rbase + r;
      const float fs = invsx[trow] * winv;
      const long ob = (long)trow * OUT_DIM + n0 + wc * 64 + fr;
#pragma unroll
      for (int ni = 0; ni < 4; ++ni) {
        out[ob + ni * 16] = (float)acc[mi][ni][r] * fs;
      }
    }
  }
}

extern "C" void kernel_launch(void* const* d_in, const int* in_sizes, int n_in,
                              void* d_out, int out_size, void* d_ws, size_t ws_size,
                              hipStream_t stream) {
  const void* x  = d_in[0];   // [4,2048,4096]  fp32 (bf16 auto-probed fallback)
  const void* w  = d_in[1];   // [11008,4096]
  const void* nw = d_in[2];   // [4096], exactly ones -> dtype probe
  float* out = (float*)d_out; // fp32 [8192,11008]

  char* ws = (char*)d_ws;
  float*  hdr     = (float*)ws;                    // [0]=wscale, [1]=1/wscale
  double* partial = (double*)(ws + 1024);          // 2048 doubles
  float*  invsx   = (float*)(ws + 20480);          // 8192 floats
  int8_t* qx      = (int8_t*)(ws + (1L << 20));            // 32 MB
  int8_t* qw      = (int8_t*)(ws + 36L * (1L << 20));      // 44 MB

  hipLaunchKernelGGL(k_wabs,   dim3(2048),   dim3(256), 0, stream, w, nw, partial);
  hipLaunchKernelGGL(k_wscale, dim3(1),      dim3(256), 0, stream, partial, hdr);
  hipLaunchKernelGGL(k_act,    dim3(TOKENS), dim3(256), 0, stream, x, nw, qx, invsx);
  hipLaunchKernelGGL(k_wq,     dim3(22016),  dim3(256), 0, stream, w, nw, hdr, qw);
  hipLaunchKernelGGL(k_gemm,   dim3(32 * 43), dim3(512), 0, stream,
                     qx, qw, invsx, hdr, out);
}